// Round 4
// baseline (1114.390 us; speedup 1.0000x reference)
//
#include <hip/hip_runtime.h>
#include <hip/hip_bf16.h>

// ScaledDotProductAttention: B=2,H=16,S=2048,D=64 -> (output[B,H,S,D], weights[B,H,S,S]).
// Inputs float32, outputs FLOAT32. Two-pass flash-with-weights, bf16 MFMA 16x16x32.
// R6 == R5 with compile fix: __builtin_nontemporal_store requires ext_vector_type, not
// HIP float4 -> store via f32x4. Design unchanged:
//  - raw s_barrier + lgkmcnt(0) (no vmcnt drain) so global loads stay in flight.
//  - 1 barrier/chunk: Vt/Msk double-buffered (write p^1 from regs while computing p).
//  - K never touches LDS: per-wave direct dwordx4 A-frag loads, depth-2 tile pipeline.
//  - Swapped MFMA operands (S^T = K x Q^T, O^T = V^T x W^T): row-per-lane ownership ->
//    float4 nt weight stores, 1 ds_read_b32 mask/tile, b64 Wt writes, float4 O stores.
//  - Wt col XOR-swizzle (l15&7)<<3.

namespace {

constexpr int kS = 2048;
constexpr int kD = 64;
constexpr int kBH = 32;            // B*H
constexpr int kTQW = 16;           // q rows per wave
constexpr int kNW = 4;             // waves per block
constexpr int kTQB = kTQW * kNW;   // 64 q rows per block
constexpr int kChunk = 64;         // k rows per chunk
constexpr int kNC = kS / kChunk;   // 32 chunks
constexpr int kNT = kNC * 4;       // 128 k-tiles of 16 rows
constexpr int kNB = kBH * (kS / kTQB);           // 1024 blocks
constexpr size_t kWOff = (size_t)kBH * kS * kD;  // weights offset in d_out

typedef __attribute__((ext_vector_type(8))) short bf16x8;
typedef __attribute__((ext_vector_type(4))) float f32x4;
typedef __attribute__((ext_vector_type(2))) unsigned u32x2;

__device__ inline short f2bf(float f) {
  union { float f; unsigned u; } x; x.f = f;
  return (short)((x.u + 0x7fffu + ((x.u >> 16) & 1u)) >> 16);  // RNE
}

__device__ inline unsigned pk2bf(float a, float b) {
  return (unsigned)(unsigned short)f2bf(a) | ((unsigned)(unsigned short)f2bf(b) << 16);
}

__device__ inline bf16x8 cvt8(float4 a, float4 b, float scale) {
  bf16x8 f;
  f[0] = f2bf(a.x * scale); f[1] = f2bf(a.y * scale);
  f[2] = f2bf(a.z * scale); f[3] = f2bf(a.w * scale);
  f[4] = f2bf(b.x * scale); f[5] = f2bf(b.y * scale);
  f[6] = f2bf(b.z * scale); f[7] = f2bf(b.w * scale);
  return f;
}

// Barrier that does NOT drain vmcnt: LDS writes made visible (lgkmcnt(0)), in-flight
// global loads survive. Compiler-level fence via "memory" clobbers pins program order.
__device__ inline void block_sync_lds() {
  asm volatile("s_waitcnt lgkmcnt(0)" ::: "memory");
  __builtin_amdgcn_s_barrier();
  asm volatile("" ::: "memory");
}

__global__ __launch_bounds__(256, 4) void attn_fused(
    const float* __restrict__ qg, const float* __restrict__ kg,
    const float* __restrict__ vg, const unsigned int* __restrict__ mg,
    float* __restrict__ outg) {
  __shared__ __align__(16) short Vt[2][kD][72];            // bf16 V^T [d][krel-pair swz]
  __shared__ __align__(16) unsigned char Msk[2][kTQB][80]; // mask bytes [qlocal][krel]
  __shared__ __align__(16) short Wt[kNW][kTQW][72];        // bf16 W [qlocal][krel^swz]

  const int tid  = threadIdx.x;
  const int wv   = tid >> 6;
  const int lane = tid & 63;
  const int l15  = lane & 15;
  const int quad = lane >> 4;

  // XCD-chunked bijective swizzle (1024 % 8 == 0): same-bh blocks share one XCD's L2.
  const int bid  = blockIdx.x;
  const int work = ((bid & 7) << 7) | (bid >> 3);
  const int qt   = work & 31;
  const int bh   = work >> 5;
  const int b    = bh >> 4;          // H = 16
  const int q0b  = qt * kTQB;

  // ---- mask encoding detection (uint8 | int32 | float32 | bf16), element test != 0 ----
  int allW32 = 1, allI32 = 1, allBF = 1;
#pragma unroll
  for (int i = 0; i < 64; ++i) {
    const unsigned u = mg[i];
    const unsigned lo = u & 0xFFFFu, hi = u >> 16;
    allW32 &= (int)(u == 0u || u == 0x3F800000u);
    allI32 &= (int)(u == 0u || u == 1u);
    allBF  &= (int)((lo == 0u || lo == 0x3F80u) && (hi == 0u || hi == 0x3F80u));
  }
  int msz;
  if (allI32)      msz = 4;
  else if (allW32) msz = 4;
  else if (allBF)  msz = 2;
  else             msz = 1;
  const unsigned char* mB = (const unsigned char*)mg + (size_t)b * kS * kS * msz;

  const float* qbase = qg + (size_t)bh * kS * kD;
  const float* kbase = kg + (size_t)bh * kS * kD;
  const float* vbase = vg + (size_t)bh * kS * kD;
  float* obase = outg + (size_t)bh * kS * kD;
  float* wbase = outg + kWOff + (size_t)bh * kS * kS;

  const int qrow = q0b + wv * kTQW + l15;   // this lane's q row (swapped layout: row-per-lane)

  // ---- Q fragments (B-operand of swapped QK^T), pre-scaled by 1/8, in registers ----
  bf16x8 aq[2];
#pragma unroll
  for (int dh = 0; dh < 2; ++dh) {
    const float* p = qbase + (size_t)qrow * kD + dh * 32 + quad * 8;
    aq[dh] = cvt8(*(const float4*)p, *(const float4*)(p + 4), 0.125f);
  }

  // ---- K tile pipeline: per-wave direct loads, depth 2 (banks kb0/kb1) ----
  // Tile tt (16 k-rows): lane loads K[tt*16+l15][quad*8 + (0..7)] and [32+quad*8 + (0..7)].
  float4 kb0[4], kb1[4];
  auto k_issue0 = [&](int tt) {
    const float* p = kbase + (size_t)(tt * 16 + l15) * kD + quad * 8;
    kb0[0] = *(const float4*)p;        kb0[1] = *(const float4*)(p + 4);
    kb0[2] = *(const float4*)(p + 32); kb0[3] = *(const float4*)(p + 36);
  };
  auto k_issue1 = [&](int tt) {
    const float* p = kbase + (size_t)(tt * 16 + l15) * kD + quad * 8;
    kb1[0] = *(const float4*)p;        kb1[1] = *(const float4*)(p + 4);
    kb1[2] = *(const float4*)(p + 32); kb1[3] = *(const float4*)(p + 36);
  };

  // ---- V / mask register staging (written to LDS buf p^1 while computing buf p) ----
  const int si = tid >> 2;          // staging row 0..63
  const int sj = (tid & 3) << 4;    // col segment
  const int vd = (tid & 7) << 3;    // V: d base
  const int vk = (tid >> 3) << 1;   // V: even krel pair base
  float4 rv[4];
  uint4 rmq;

  auto v_issue = [&](int c) {
    const float* p = vbase + (size_t)(c * kChunk + vk) * kD + vd;
    rv[0] = *(const float4*)p;        rv[1] = *(const float4*)(p + 4);
    rv[2] = *(const float4*)(p + kD); rv[3] = *(const float4*)(p + kD + 4);
  };
  auto v_write = [&](int buf) {
    const float* lo = (const float*)&rv[0];
    const float* hi = (const float*)&rv[2];
#pragma unroll
    for (int d = 0; d < 8; ++d) {
      const int dd = vd + d;
      const int ps = (vk >> 1) ^ (((dd >> 3) & 7) << 2);
      const unsigned u = (unsigned)(unsigned short)f2bf(lo[d]) |
                         ((unsigned)(unsigned short)f2bf(hi[d]) << 16);
      *(unsigned*)&Vt[buf][dd][2 * ps] = u;
    }
  };

  auto m_issue = [&](int c) {
    if (msz == 1)
      rmq = *(const uint4*)(mB + (size_t)(q0b + si) * kS + (size_t)(c * kChunk + sj));
  };
  auto m_write = [&](int buf, int c) {
    if (msz == 1) {
      *(uint4*)&Msk[buf][si][sj] = rmq;   // bytes already 0/1
    } else if (msz == 4) {
      const size_t eoff = (size_t)(q0b + si) * kS + (size_t)(c * kChunk + sj);
      const unsigned int* p = (const unsigned int*)mB + eoff;   // int32 AND f32: word != 0
      unsigned int* dst = (unsigned int*)&Msk[buf][si][sj];
#pragma unroll
      for (int g = 0; g < 4; ++g) {
        uint4 e = *(const uint4*)(p + 4 * g);
        dst[g] = (e.x ? 1u : 0u) | ((e.y ? 1u : 0u) << 8) |
                 ((e.z ? 1u : 0u) << 16) | ((e.w ? 1u : 0u) << 24);
      }
    } else {  // msz == 2, bf16 0/1.0
      const size_t eoff = (size_t)(q0b + si) * kS + (size_t)(c * kChunk + sj);
      const unsigned int* p = (const unsigned int*)((const unsigned short*)mB + eoff);
      unsigned int* dst = (unsigned int*)&Msk[buf][si][sj];
#pragma unroll
      for (int g = 0; g < 4; ++g) {
        const unsigned int a = p[2 * g], cc = p[2 * g + 1];
        dst[g] = ((a & 0xFFFFu) ? 1u : 0u) | (((a >> 16) ? 1u : 0u) << 8) |
                 (((cc & 0xFFFFu) ? 1u : 0u) << 16) | (((cc >> 16) ? 1u : 0u) << 24);
      }
    }
  };

  const int mrow = wv * kTQW + l15;   // Msk row this lane reads

  // ================= Pass A: l = sum_k exp(s) per q row =================
  float lsum = 0.f;
  m_issue(0);
  k_issue0(0); k_issue1(1);
  m_write(0, 0);
  m_issue(1);
  block_sync_lds();
  int p = 0;
  for (int c = 0; c < kNC; ++c) {
    if (c + 1 < kNC) m_write(p ^ 1, c + 1);
    if (c + 2 < kNC) m_issue(c + 2);
#pragma unroll
    for (int t = 0; t < 4; ++t) {
      bf16x8 f0, f1;
      if ((t & 1) == 0) { f0 = cvt8(kb0[0], kb0[1], 1.f); f1 = cvt8(kb0[2], kb0[3], 1.f); }
      else              { f0 = cvt8(kb1[0], kb1[1], 1.f); f1 = cvt8(kb1[2], kb1[3], 1.f); }
      const int nt_ = c * 4 + t + 2;
      if (nt_ < kNT) { if (t & 1) k_issue1(nt_); else k_issue0(nt_); }
      f32x4 acc = {0.f, 0.f, 0.f, 0.f};
      acc = __builtin_amdgcn_mfma_f32_16x16x32_bf16(f0, aq[0], acc, 0, 0, 0);
      acc = __builtin_amdgcn_mfma_f32_16x16x32_bf16(f1, aq[1], acc, 0, 0, 0);
      // S^T tile: lane holds S[q=l15][k = t*16 + quad*4 + r]
      const unsigned mu = *(const unsigned*)&Msk[p][mrow][t * 16 + quad * 4];
#pragma unroll
      for (int r = 0; r < 4; ++r) {
        const float e = __expf(acc[r]);
        lsum += ((mu >> (8 * r)) & 0xFFu) ? 1.0f : e;   // masked -> exp(-1e-9) == 1.0f
      }
    }
    block_sync_lds();
    p ^= 1;
  }

  // reduce across the 4 quads holding this q row's column subsets
  lsum += __shfl_xor(lsum, 16);
  lsum += __shfl_xor(lsum, 32);
  const float inv = 1.0f / lsum;

  // ================= Pass B: weights (fp32 f32x4 nt) + PV (O^T) =================
  f32x4 acco[4];
#pragma unroll
  for (int d = 0; d < 4; ++d) acco[d] = (f32x4){0.f, 0.f, 0.f, 0.f};

  v_issue(0); m_issue(0);
  k_issue0(0); k_issue1(1);
  v_write(0); m_write(0, 0);
  v_issue(1); m_issue(1);
  block_sync_lds();
  p = 0;
  float* const wrow = wbase + (size_t)qrow * kS;
  const int swz = (l15 & 7) << 3;
  for (int c = 0; c < kNC; ++c) {
    if (c + 1 < kNC) { v_write(p ^ 1); m_write(p ^ 1, c + 1); }
    if (c + 2 < kNC) { v_issue(c + 2); m_issue(c + 2); }
#pragma unroll
    for (int t = 0; t < 4; ++t) {
      bf16x8 f0, f1;
      if ((t & 1) == 0) { f0 = cvt8(kb0[0], kb0[1], 1.f); f1 = cvt8(kb0[2], kb0[3], 1.f); }
      else              { f0 = cvt8(kb1[0], kb1[1], 1.f); f1 = cvt8(kb1[2], kb1[3], 1.f); }
      const int nt_ = c * 4 + t + 2;
      if (nt_ < kNT) { if (t & 1) k_issue1(nt_); else k_issue0(nt_); }
      f32x4 acc = {0.f, 0.f, 0.f, 0.f};
      acc = __builtin_amdgcn_mfma_f32_16x16x32_bf16(f0, aq[0], acc, 0, 0, 0);
      acc = __builtin_amdgcn_mfma_f32_16x16x32_bf16(f1, aq[1], acc, 0, 0, 0);
      const unsigned mu = *(const unsigned*)&Msk[p][mrow][t * 16 + quad * 4];
      const float w0 = ((mu       & 0xFFu) ? 1.0f : __expf(acc[0])) * inv;
      const float w1 = ((mu >> 8  & 0xFFu) ? 1.0f : __expf(acc[1])) * inv;
      const float w2 = ((mu >> 16 & 0xFFu) ? 1.0f : __expf(acc[2])) * inv;
      const float w3 = ((mu >> 24        ) ? 1.0f : __expf(acc[3])) * inv;
      // Wt (bf16, for PV A/B-frag): row l15, 4 consecutive cols, XOR-swizzled, b64 write
      u32x2 uu = {pk2bf(w0, w1), pk2bf(w2, w3)};
      *(u32x2*)&Wt[wv][l15][(t * 16 + quad * 4) ^ swz] = uu;
      // fp32 weights: 4 consecutive cols -> one nt dwordx4 (ext_vector type for builtin)
      f32x4 wq = {w0, w1, w2, w3};
      __builtin_nontemporal_store(wq, (f32x4*)(wrow + c * kChunk + t * 16 + quad * 4));
    }
    // PV: O^T = V^T x W^T. A-frag = V^T (from Vt), B-frag = W (from Wt, own row l15).
#pragma unroll
    for (int ks = 0; ks < 2; ++ks) {
      bf16x8 aw = *(const bf16x8*)&Wt[wv][l15][(ks * 32 + quad * 8) ^ swz];
#pragma unroll
      for (int dt = 0; dt < 4; ++dt) {
        const int dd = dt * 16 + l15;
        const int psb = (ks * 16 + quad * 4) ^ (((dd >> 3) & 7) << 2);
        bf16x8 bv = *(const bf16x8*)&Vt[p][dd][2 * psb];
        acco[dt] = __builtin_amdgcn_mfma_f32_16x16x32_bf16(bv, aw, acco[dt], 0, 0, 0);
      }
    }
    block_sync_lds();
    p ^= 1;
  }

  // ---- epilogue: O^T lane layout -> lane holds O[q=l15][d = dt*16+quad*4+r]: f32x4 ----
#pragma unroll
  for (int dt = 0; dt < 4; ++dt) {
    f32x4 o = acco[dt];
    __builtin_nontemporal_store(o, (f32x4*)(obase + (size_t)qrow * kD + dt * 16 + quad * 4));
  }
}

}  // namespace

extern "C" void kernel_launch(void* const* d_in, const int* in_sizes, int n_in,
                              void* d_out, int out_size, void* d_ws, size_t ws_size,
                              hipStream_t stream) {
  const float* q = (const float*)d_in[0];
  const float* k = (const float*)d_in[1];
  const float* v = (const float*)d_in[2];
  const unsigned int* mask = (const unsigned int*)d_in[3];
  float* out = (float*)d_out;  // fp32 output buffer (output ++ weights)
  attn_fused<<<dim3(kNB), dim3(256), 0, stream>>>(q, k, v, mask, out);
}

// Round 5
// 830.859 us; speedup vs baseline: 1.3413x; 1.3413x over previous
//
#include <hip/hip_runtime.h>
#include <hip/hip_bf16.h>

// ScaledDotProductAttention: B=2,H=16,S=2048,D=64 -> (output[B,H,S,D], weights[B,H,S,S]).
// Inputs float32, outputs FLOAT32. Two-pass flash-with-weights, bf16 MFMA 16x16x32.
// R7 = best-of-R2-and-R6:
//  - K staged in LDS once per block (R2 traffic structure; R6's per-wave K loads doubled
//    FETCH to 643 MB and regressed 370->683 us).
//  - Raw s_barrier + lgkmcnt(0) only (m201 pattern): __syncthreads' vmcnt(0) drain was
//    serializing prefetch loads AND the 512 MB weight-store stream at every chunk.
//  - Pass A: true 1-barrier/chunk double-buffer; K buf1 aliases Vt space, Msk buf1
//    aliases Wt space (both unused in pass A). LDS total exactly 32768 B -> 4 blocks/CU.
//  - R6-verified pieces kept: swapped MFMA (S^T = K x Q^T, O^T = V^T x W^T), f32x4 nt
//    weight stores, b64 Wt writes + XOR swizzle, Vt pair-swizzle, scalar lsum,
//    f32x4 O stores. All bit-identical numerics (R6 passed, absmax 0.0039).

namespace {

constexpr int kS = 2048;
constexpr int kD = 64;
constexpr int kBH = 32;            // B*H
constexpr int kTQW = 16;           // q rows per wave
constexpr int kNW = 4;             // waves per block
constexpr int kTQB = kTQW * kNW;   // 64 q rows per block
constexpr int kChunk = 64;         // k rows per chunk
constexpr int kNC = kS / kChunk;   // 32 chunks
constexpr int kNB = kBH * (kS / kTQB);           // 1024 blocks
constexpr size_t kWOff = (size_t)kBH * kS * kD;  // weights offset in d_out

typedef __attribute__((ext_vector_type(8))) short bf16x8;
typedef __attribute__((ext_vector_type(4))) float f32x4;
typedef __attribute__((ext_vector_type(2))) unsigned u32x2;

__device__ inline short f2bf(float f) {
  union { float f; unsigned u; } x; x.f = f;
  return (short)((x.u + 0x7fffu + ((x.u >> 16) & 1u)) >> 16);  // RNE
}

__device__ inline unsigned pk2bf(float a, float b) {
  return (unsigned)(unsigned short)f2bf(a) | ((unsigned)(unsigned short)f2bf(b) << 16);
}

__device__ inline bf16x8 cvt8(float4 a, float4 b, float scale) {
  bf16x8 f;
  f[0] = f2bf(a.x * scale); f[1] = f2bf(a.y * scale);
  f[2] = f2bf(a.z * scale); f[3] = f2bf(a.w * scale);
  f[4] = f2bf(b.x * scale); f[5] = f2bf(b.y * scale);
  f[6] = f2bf(b.z * scale); f[7] = f2bf(b.w * scale);
  return f;
}

// Barrier that does NOT drain vmcnt: LDS writes made visible (lgkmcnt(0)); in-flight
// global loads AND stores survive. "memory" clobbers pin compiler ordering.
__device__ inline void block_sync_lds() {
  asm volatile("s_waitcnt lgkmcnt(0)" ::: "memory");
  __builtin_amdgcn_s_barrier();
  asm volatile("" ::: "memory");
}

__global__ __launch_bounds__(256, 4) void attn_fused(
    const float* __restrict__ qg, const float* __restrict__ kg,
    const float* __restrict__ vg, const unsigned int* __restrict__ mg,
    float* __restrict__ outg) {
  // One 32768 B LDS pool, carved (shorts):
  //  [0,4608)      Kt0: K chunk buf0 [64][72]
  //  [4608,9216)   Kt1: pass A K buf1 / pass B V^T [64][72] (pair-swizzled)
  //  [9216,13824)  Wts: pass B per-wave W [64][72]; pass A Msk buf1 (bytes, 5120 of 9216)
  //  [13824,16384) Msk0 bytes [64][80]
  __shared__ __align__(16) short SH[16384];
  short (*Kt0)[72] = (short(*)[72])SH;
  short (*Kt1)[72] = (short(*)[72])(SH + 4608);
  short (*Wts)[72] = (short(*)[72])(SH + 9216);
  unsigned char (*Msk0)[80] = (unsigned char(*)[80])(SH + 13824);
  unsigned char (*Msk1)[80] = (unsigned char(*)[80])(SH + 9216);

  const int tid  = threadIdx.x;
  const int wv   = tid >> 6;
  const int lane = tid & 63;
  const int l15  = lane & 15;
  const int quad = lane >> 4;

  // XCD-chunked bijective swizzle (1024 % 8 == 0): same-bh blocks share one XCD's L2.
  const int bid  = blockIdx.x;
  const int work = ((bid & 7) << 7) | (bid >> 3);
  const int qt   = work & 31;
  const int bh   = work >> 5;
  const int b    = bh >> 4;          // H = 16
  const int q0b  = qt * kTQB;

  // ---- mask encoding detection (uint8 | int32 | float32 | bf16), element test != 0 ----
  int allW32 = 1, allI32 = 1, allBF = 1;
#pragma unroll
  for (int i = 0; i < 64; ++i) {
    const unsigned u = mg[i];
    const unsigned lo = u & 0xFFFFu, hi = u >> 16;
    allW32 &= (int)(u == 0u || u == 0x3F800000u);
    allI32 &= (int)(u == 0u || u == 1u);
    allBF  &= (int)((lo == 0u || lo == 0x3F80u) && (hi == 0u || hi == 0x3F80u));
  }
  int msz;
  if (allI32)      msz = 4;
  else if (allW32) msz = 4;
  else if (allBF)  msz = 2;
  else             msz = 1;
  const unsigned char* mB = (const unsigned char*)mg + (size_t)b * kS * kS * msz;

  const float* qbase = qg + (size_t)bh * kS * kD;
  const float* kbase = kg + (size_t)bh * kS * kD;
  const float* vbase = vg + (size_t)bh * kS * kD;
  float* obase = outg + (size_t)bh * kS * kD;
  float* wbase = outg + kWOff + (size_t)bh * kS * kS;

  const int qrow = q0b + wv * kTQW + l15;   // row-per-lane (swapped layout)
  const int mrow = wv * kTQW + l15;

  // ---- Q fragments (B-operand of swapped QK^T), pre-scaled by 1/8, in registers ----
  bf16x8 aq[2];
#pragma unroll
  for (int dh = 0; dh < 2; ++dh) {
    const float* p = qbase + (size_t)qrow * kD + dh * 32 + quad * 8;
    aq[dh] = cvt8(*(const float4*)p, *(const float4*)(p + 4), 0.125f);
  }

  // ---- staging thread maps ----
  const int si = tid >> 2;          // K/M row 0..63
  const int sj = (tid & 3) << 4;    // K col segment 0/16/32/48
  const int vd = (tid & 7) << 3;    // V: d base
  const int vk = (tid >> 3) << 1;   // V: even krel pair base
  float4 rk[4], rv[4];
  uint4 rmq;

  auto k_issue = [&](int c) {
    const float* p = kbase + (size_t)(c * kChunk + si) * kD + sj;
    rk[0] = *(const float4*)p;       rk[1] = *(const float4*)(p + 4);
    rk[2] = *(const float4*)(p + 8); rk[3] = *(const float4*)(p + 12);
  };
  auto k_write = [&](short (*Kdst)[72]) {
    *(bf16x8*)&Kdst[si][sj]     = cvt8(rk[0], rk[1], 1.0f);
    *(bf16x8*)&Kdst[si][sj + 8] = cvt8(rk[2], rk[3], 1.0f);
  };

  auto v_issue = [&](int c) {
    const float* p = vbase + (size_t)(c * kChunk + vk) * kD + vd;
    rv[0] = *(const float4*)p;        rv[1] = *(const float4*)(p + 4);
    rv[2] = *(const float4*)(p + kD); rv[3] = *(const float4*)(p + kD + 4);
  };
  // V^T into Kt1: pair (vk,vk+1) packed per dword, pair index XOR-swizzled by d-group.
  auto v_write = [&]() {
    const float* lo = (const float*)&rv[0];
    const float* hi = (const float*)&rv[2];
#pragma unroll
    for (int d = 0; d < 8; ++d) {
      const int dd = vd + d;
      const int ps = (vk >> 1) ^ (((dd >> 3) & 7) << 2);
      const unsigned u = pk2bf(lo[d], hi[d]);
      *(unsigned*)&Kt1[dd][2 * ps] = u;
    }
  };

  auto m_issue = [&](int c) {
    if (msz == 1)
      rmq = *(const uint4*)(mB + (size_t)(q0b + si) * kS + (size_t)(c * kChunk + sj));
  };
  auto m_write = [&](unsigned char (*Mdst)[80], int c) {
    if (msz == 1) {
      *(uint4*)&Mdst[si][sj] = rmq;   // bytes already 0/1
    } else if (msz == 4) {
      const size_t eoff = (size_t)(q0b + si) * kS + (size_t)(c * kChunk + sj);
      const unsigned int* p = (const unsigned int*)mB + eoff;   // int32 AND f32: word != 0
      unsigned int* dst = (unsigned int*)&Mdst[si][sj];
#pragma unroll
      for (int g = 0; g < 4; ++g) {
        uint4 e = *(const uint4*)(p + 4 * g);
        dst[g] = (e.x ? 1u : 0u) | ((e.y ? 1u : 0u) << 8) |
                 ((e.z ? 1u : 0u) << 16) | ((e.w ? 1u : 0u) << 24);
      }
    } else {  // msz == 2, bf16 0/1.0
      const size_t eoff = (size_t)(q0b + si) * kS + (size_t)(c * kChunk + sj);
      const unsigned int* p = (const unsigned int*)((const unsigned short*)mB + eoff);
      unsigned int* dst = (unsigned int*)&Mdst[si][sj];
#pragma unroll
      for (int g = 0; g < 4; ++g) {
        const unsigned int a = p[2 * g], cc = p[2 * g + 1];
        dst[g] = ((a & 0xFFFFu) ? 1u : 0u) | (((a >> 16) ? 1u : 0u) << 8) |
                 (((cc & 0xFFFFu) ? 1u : 0u) << 16) | (((cc >> 16) ? 1u : 0u) << 24);
      }
    }
  };

  // ================= Pass A: l = sum_k exp(s); 1 barrier/chunk, dbuf =================
  float lsum = 0.f;
  k_issue(0); m_issue(0);
  k_write(Kt0); m_write(Msk0, 0);
  k_issue(1); m_issue(1);
  block_sync_lds();
  for (int c = 0; c < kNC; ++c) {
    short (*K)[72] = (c & 1) ? Kt1 : Kt0;
    const unsigned char (*M)[80] =
        (c & 1) ? (const unsigned char (*)[80])Msk1 : (const unsigned char (*)[80])Msk0;
    // stage chunk c+1 into the other buffer (its last readers finished at barrier c-1)
    if (c + 1 < kNC) { k_write((c & 1) ? Kt0 : Kt1); m_write((c & 1) ? Msk0 : Msk1, c + 1); }
    if (c + 2 < kNC) { k_issue(c + 2); m_issue(c + 2); }
#pragma unroll
    for (int t = 0; t < 4; ++t) {
      bf16x8 f0 = *(const bf16x8*)&K[t * 16 + l15][quad * 8];
      bf16x8 f1 = *(const bf16x8*)&K[t * 16 + l15][32 + quad * 8];
      f32x4 acc = {0.f, 0.f, 0.f, 0.f};
      acc = __builtin_amdgcn_mfma_f32_16x16x32_bf16(f0, aq[0], acc, 0, 0, 0);
      acc = __builtin_amdgcn_mfma_f32_16x16x32_bf16(f1, aq[1], acc, 0, 0, 0);
      // S^T tile: lane holds S[q=l15][k = t*16 + quad*4 + r]
      const unsigned mu = *(const unsigned*)&M[mrow][t * 16 + quad * 4];
#pragma unroll
      for (int r = 0; r < 4; ++r) {
        const float e = __expf(acc[r]);
        lsum += ((mu >> (8 * r)) & 0xFFu) ? 1.0f : e;   // masked -> exp(-1e-9) == 1.0f
      }
    }
    block_sync_lds();
  }

  // reduce across the 4 quads holding this q row's column subsets
  lsum += __shfl_xor(lsum, 16);
  lsum += __shfl_xor(lsum, 32);
  const float inv = 1.0f / lsum;

  // ================= Pass B: weights (f32x4 nt) + PV (O^T); 2 barriers/chunk ==========
  f32x4 acco[4];
#pragma unroll
  for (int d = 0; d < 4; ++d) acco[d] = (f32x4){0.f, 0.f, 0.f, 0.f};

  k_issue(0); v_issue(0); m_issue(0);
  k_write(Kt0); v_write(); m_write(Msk0, 0);
  k_issue(1); v_issue(1); m_issue(1);
  block_sync_lds();
  float* const wrow = wbase + (size_t)qrow * kS;
  const int swz = (l15 & 7) << 3;
  for (int c = 0; c < kNC; ++c) {
#pragma unroll
    for (int t = 0; t < 4; ++t) {
      bf16x8 f0 = *(const bf16x8*)&Kt0[t * 16 + l15][quad * 8];
      bf16x8 f1 = *(const bf16x8*)&Kt0[t * 16 + l15][32 + quad * 8];
      f32x4 acc = {0.f, 0.f, 0.f, 0.f};
      acc = __builtin_amdgcn_mfma_f32_16x16x32_bf16(f0, aq[0], acc, 0, 0, 0);
      acc = __builtin_amdgcn_mfma_f32_16x16x32_bf16(f1, aq[1], acc, 0, 0, 0);
      const unsigned mu = *(const unsigned*)&Msk0[mrow][t * 16 + quad * 4];
      const float w0 = ((mu       & 0xFFu) ? 1.0f : __expf(acc[0])) * inv;
      const float w1 = ((mu >> 8  & 0xFFu) ? 1.0f : __expf(acc[1])) * inv;
      const float w2 = ((mu >> 16 & 0xFFu) ? 1.0f : __expf(acc[2])) * inv;
      const float w3 = ((mu >> 24        ) ? 1.0f : __expf(acc[3])) * inv;
      // Wt (bf16, PV B-frag): row l15, 4 consecutive cols, XOR-swizzled, b64 write.
      // Same-wave write/read only -> no barrier needed (lgkmcnt dependency).
      u32x2 uu = {pk2bf(w0, w1), pk2bf(w2, w3)};
      *(u32x2*)&Wts[wv * kTQW + l15][(t * 16 + quad * 4) ^ swz] = uu;
      // fp32 weights: 4 consecutive cols -> one nt dwordx4
      f32x4 wq = {w0, w1, w2, w3};
      __builtin_nontemporal_store(wq, (f32x4*)(wrow + c * kChunk + t * 16 + quad * 4));
    }
    // PV: O^T = V^T x W^T. A-frag = V^T (Kt1, deswizzled), B-frag = own W row.
    __builtin_amdgcn_s_setprio(1);
#pragma unroll
    for (int ks = 0; ks < 2; ++ks) {
      bf16x8 aw = *(const bf16x8*)&Wts[wv * kTQW + l15][(ks * 32 + quad * 8) ^ swz];
#pragma unroll
      for (int dt = 0; dt < 4; ++dt) {
        const int dd = dt * 16 + l15;
        const int psb = (ks * 16 + quad * 4) ^ (((dd >> 3) & 7) << 2);
        bf16x8 bv = *(const bf16x8*)&Kt1[dd][2 * psb];
        acco[dt] = __builtin_amdgcn_mfma_f32_16x16x32_bf16(bv, aw, acco[dt], 0, 0, 0);
      }
    }
    __builtin_amdgcn_s_setprio(0);
    block_sync_lds();                 // all reads of Kt0/Kt1/Msk0 done
    if (c + 1 < kNC) { k_write(Kt0); v_write(); m_write(Msk0, c + 1); }
    if (c + 2 < kNC) { k_issue(c + 2); v_issue(c + 2); m_issue(c + 2); }
    block_sync_lds();                 // staged chunk c+1 visible
  }

  // ---- epilogue: lane holds O[q=l15-row][d = dt*16+quad*4+r] -> f32x4 nt stores ----
#pragma unroll
  for (int dt = 0; dt < 4; ++dt) {
    f32x4 o = acco[dt];
    __builtin_nontemporal_store(o, (f32x4*)(obase + (size_t)qrow * kD + dt * 16 + quad * 4));
  }
}

}  // namespace

extern "C" void kernel_launch(void* const* d_in, const int* in_sizes, int n_in,
                              void* d_out, int out_size, void* d_ws, size_t ws_size,
                              hipStream_t stream) {
  const float* q = (const float*)d_in[0];
  const float* k = (const float*)d_in[1];
  const float* v = (const float*)d_in[2];
  const unsigned int* mask = (const unsigned int*)d_in[3];
  float* out = (float*)d_out;  // fp32 output buffer (output ++ weights)
  attn_fused<<<dim3(kNB), dim3(256), 0, stream>>>(q, k, v, mask, out);
}